// Round 2
// baseline (61426.056 us; speedup 1.0000x reference)
//
#include <hip/hip_runtime.h>

// dims
#define Bv 16
#define Tv 256
#define Nv 128
#define NEGSC (-1.7677669529663689e8f)   // NEG / sqrt(32)
#define INVS  (0.17677669529663687f)     // 1 / sqrt(32)

// ---------------- conv1 lift: x[b,t,n,c] = values[b,t,n]*w[c] + b[c] ----------------
__global__ __launch_bounds__(256) void k_lift(const float* __restrict__ values,
    const float* __restrict__ w, const float* __restrict__ b, float* __restrict__ x) {
  int i = blockIdx.x * 256 + threadIdx.x;     // over B*T*N*C = 33554432
  int c = i & 63;
  int r = i >> 6;
  x[i] = values[r] * w[c] + b[c];
}

// ---------------- layernorm over C=64, one wave per row ----------------
__global__ __launch_bounds__(256) void k_ln(const float* __restrict__ in, float* __restrict__ out,
    const float* __restrict__ g, const float* __restrict__ b) {
  int row = blockIdx.x * 4 + (threadIdx.x >> 6);
  int c = threadIdx.x & 63;
  float v = in[(size_t)row * 64 + c];
  float s = v;
  #pragma unroll
  for (int o = 32; o > 0; o >>= 1) s += __shfl_xor(s, o, 64);
  float mu = s * (1.f / 64.f);
  float d = v - mu;
  float q = d * d;
  #pragma unroll
  for (int o = 32; o > 0; o >>= 1) q += __shfl_xor(q, o, 64);
  out[(size_t)row * 64 + c] = d * rsqrtf(q * (1.f / 64.f) + 1e-5f) * g[c] + b[c];
}

// ------------- transpose chunk: in[CB,T,N,C] -> out[CB,N,T,C] (grid = CB*8192) -------
__global__ __launch_bounds__(256) void k_tr(const float* __restrict__ in, float* __restrict__ out) {
  int i = blockIdx.x * 256 + threadIdx.x;     // output index over [CB,N,T,C]
  int c = i & 63;
  int r = i >> 6;              // (b*N+n)*T + t
  int t = r & 255;
  int bn = r >> 8;
  int n = bn & 127;
  int b = bn >> 7;
  out[i] = in[(size_t)((((b << 8) + t) << 7) + n) * 64 + c];
}

// ---------------- generic f32 GEMM: C[M,Nn] = A[M,K] x B[K,Nn]  (+bias,+res,relu) ----
// res may alias Cm (element-wise read-then-write by same thread).
__global__ __launch_bounds__(256) void k_gemm(const float* __restrict__ A,
    const float* __restrict__ Bm, float* __restrict__ Cm,
    int M, int Nn, int K,
    const float* __restrict__ bias, const float* __restrict__ res, int relu) {
  __shared__ float As[16][65];
  __shared__ float Bs[16][64];
  int m0 = blockIdx.x * 64, n0 = blockIdx.y * 64;
  int tid = threadIdx.x;
  int lr = tid >> 2, lc = tid & 3;      // A tile loader: row, float4-col
  int kb = tid >> 4, nb = tid & 15;     // B tile loader: k-row, float4-col
  int ty = tid >> 4, tx = tid & 15;     // compute mapping
  float acc[4][4] = {};
  const float* Aptr = A + (size_t)(m0 + lr) * K + lc * 4;
  const float* Bptr = Bm + (size_t)kb * Nn + n0 + nb * 4;
  for (int k0 = 0; k0 < K; k0 += 16) {
    float4 av = *(const float4*)(Aptr + k0);
    float4 bv = *(const float4*)(Bptr + (size_t)k0 * Nn);
    As[lc * 4 + 0][lr] = av.x; As[lc * 4 + 1][lr] = av.y;
    As[lc * 4 + 2][lr] = av.z; As[lc * 4 + 3][lr] = av.w;
    *(float4*)&Bs[kb][nb * 4] = bv;
    __syncthreads();
    #pragma unroll
    for (int kk = 0; kk < 16; kk++) {
      float a0 = As[kk][ty * 4 + 0], a1 = As[kk][ty * 4 + 1];
      float a2 = As[kk][ty * 4 + 2], a3 = As[kk][ty * 4 + 3];
      float b0 = Bs[kk][tx * 4 + 0], b1 = Bs[kk][tx * 4 + 1];
      float b2 = Bs[kk][tx * 4 + 2], b3 = Bs[kk][tx * 4 + 3];
      acc[0][0] += a0 * b0; acc[0][1] += a0 * b1; acc[0][2] += a0 * b2; acc[0][3] += a0 * b3;
      acc[1][0] += a1 * b0; acc[1][1] += a1 * b1; acc[1][2] += a1 * b2; acc[1][3] += a1 * b3;
      acc[2][0] += a2 * b0; acc[2][1] += a2 * b1; acc[2][2] += a2 * b2; acc[2][3] += a2 * b3;
      acc[3][0] += a3 * b0; acc[3][1] += a3 * b1; acc[3][2] += a3 * b2; acc[3][3] += a3 * b3;
    }
    __syncthreads();
  }
  #pragma unroll
  for (int ii = 0; ii < 4; ii++) {
    size_t row = m0 + ty * 4 + ii;
    #pragma unroll
    for (int jj = 0; jj < 4; jj++) {
      int col = n0 + tx * 4 + jj;
      float v = acc[ii][jj];
      if (bias) v += bias[col];
      if (res)  v += res[row * (size_t)Nn + col];
      if (relu) v = fmaxf(v, 0.f);
      Cm[row * (size_t)Nn + col] = v;
    }
  }
}

// ---------------- energy: e[b,h,q,k] = (q.k)*INVS, diag = NEG*INVS ----------------
template<int A>
__global__ __launch_bounds__(256) void k_energy(const float* __restrict__ q,
    const float* __restrict__ k, float* __restrict__ e) {
  constexpr int SH = (A == 128) ? 7 : 8;
  int bh = blockIdx.y;                         // over CB*8
  int b = bh >> 3, h = bh & 7;
  int idx = blockIdx.x * 256 + threadIdx.x;    // over A*A
  int kk = idx & (A - 1);
  int qq = idx >> SH;
  const float4* qr = (const float4*)(q + (size_t)(b * A + qq) * 256 + h * 32);
  const float4* kr = (const float4*)(k + (size_t)(b * A + kk) * 256 + h * 32);
  float s = 0.f;
  #pragma unroll
  for (int d = 0; d < 8; d++) {
    float4 a = qr[d], bb = kr[d];
    s += a.x * bb.x + a.y * bb.y + a.z * bb.z + a.w * bb.w;
  }
  e[((size_t)bh * A + qq) * A + kk] = (qq == kk) ? NEGSC : s * INVS;
}

// ---------------- softmax over last axis (row length A), one wave per row ----------
template<int A>
__global__ __launch_bounds__(256) void k_softmax(float* __restrict__ e) {
  int row = blockIdx.x * 4 + (threadIdx.x >> 6);
  int lane = threadIdx.x & 63;
  float* p = e + (size_t)row * A;
  constexpr int NVv = A / 64;
  float vals[NVv];
  float mx = -3e38f;
  #pragma unroll
  for (int j = 0; j < NVv; j++) { vals[j] = p[lane + j * 64]; mx = fmaxf(mx, vals[j]); }
  #pragma unroll
  for (int o = 32; o > 0; o >>= 1) mx = fmaxf(mx, __shfl_xor(mx, o, 64));
  float s = 0.f;
  #pragma unroll
  for (int j = 0; j < NVv; j++) { vals[j] = __expf(vals[j] - mx); s += vals[j]; }
  #pragma unroll
  for (int o = 32; o > 0; o >>= 1) s += __shfl_xor(s, o, 64);
  float r = 1.f / s;
  #pragma unroll
  for (int j = 0; j < NVv; j++) p[lane + j * 64] = vals[j] * r;
}

// -------- attention-out: out[q,d] = sum_k attn[b,h,q,k] * v[b,(k,e),h*8+vu], d=e*8+vu
//          writes plain [CB,T,N,64] layout (sp and tp go to separate buffers).
template<int A, int E, bool SP>
__global__ __launch_bounds__(256) void k_attnout(const float* __restrict__ attn,
    const float* __restrict__ v, float* __restrict__ outb) {
  __shared__ float at[16][A + 1];
  int bh = blockIdx.z;                  // over CB*8
  int b = bh >> 3, h = bh & 7;
  int q0 = blockIdx.y * 16;
  int d0 = blockIdx.x * 64;
  int tid = threadIdx.x;
  constexpr int SH = (A == 128) ? 7 : 8;
  const float* ap = attn + ((size_t)bh * A + q0) * A;
  for (int i = tid; i < 16 * A; i += 256) at[i >> SH][i & (A - 1)] = ap[i];
  __syncthreads();
  int dl = tid & 63, qg = tid >> 6;
  int d = d0 + dl;
  int e = d >> 3, vu = d & 7;
  const float* vp = v + ((size_t)b * A * E + e) * 64 + h * 8 + vu;
  float acc0 = 0.f, acc1 = 0.f, acc2 = 0.f, acc3 = 0.f;
  #pragma unroll 4
  for (int kk = 0; kk < A; kk++) {
    float bv = vp[(size_t)kk * E * 64];
    acc0 += at[qg][kk] * bv;
    acc1 += at[qg + 4][kk] * bv;
    acc2 += at[qg + 8][kk] * bv;
    acc3 += at[qg + 12][kk] * bv;
  }
  float accs[4] = {acc0, acc1, acc2, acc3};
  #pragma unroll
  for (int j = 0; j < 4; j++) {
    int qq = q0 + qg + 4 * j;
    int t_ = SP ? e : qq;
    int n_ = SP ? qq : e;
    outb[(((size_t)b * Tv + t_) * Nv + n_) * 64 + h * 8 + vu] = accs[j];
  }
}

// ---------------- zero loss accumulators ----------------
__global__ void k_zero(float* __restrict__ p) {
  if (threadIdx.x < 32) p[threadIdx.x] = 0.f;
}

// ---------------- conv2 + masked MSE partial sums ----------------
__global__ __launch_bounds__(256) void k_out_loss(const float* __restrict__ x,
    const float* __restrict__ w, const float* __restrict__ cb,
    const float* __restrict__ values, const float* __restrict__ masks,
    float* __restrict__ outp, float* __restrict__ acc) {
  int wid = threadIdx.x >> 6, lane = threadIdx.x & 63;
  float lnum = 0.f, lden = 0.f;
  int base = blockIdx.x * 64;   // 64 rows per block; all in same b (32768 rows per b)
  for (int g = 0; g < 16; g++) {
    int row = base + g * 4 + wid;
    float v = x[(size_t)row * 64 + lane] * w[lane];
    #pragma unroll
    for (int o = 32; o > 0; o >>= 1) v += __shfl_xor(v, o, 64);
    if (lane == 0) {
      float o = v + cb[0];
      outp[row] = o;
      float m = masks[row];
      float dd = o - values[row];
      lnum += m * dd * dd;
      lden += m;
    }
  }
  __shared__ float sn[4], sd[4];
  if (lane == 0) { sn[wid] = lnum; sd[wid] = lden; }
  __syncthreads();
  if (threadIdx.x == 0) {
    int b = base >> 15;
    atomicAdd(&acc[2 * b],     sn[0] + sn[1] + sn[2] + sn[3]);
    atomicAdd(&acc[2 * b + 1], sd[0] + sd[1] + sd[2] + sd[3]);
  }
}

__global__ void k_loss_final(const float* __restrict__ acc,
    const float* __restrict__ is_train, float* __restrict__ outp) {
  if (threadIdx.x == 0) {
    float s = 0.f, st = 0.f;
    for (int b = 0; b < 16; b++) {
      s  += (acc[2 * b] / acc[2 * b + 1]) * is_train[b];
      st += is_train[b];
    }
    outp[(size_t)Bv * Tv * Nv] = s / (st + 1e-5f);
  }
}

extern "C" void kernel_launch(void* const* d_in, const int* in_sizes, int n_in,
                              void* d_out, int out_size, void* d_ws, size_t ws_size,
                              hipStream_t stream) {
  const float* values  = (const float*)d_in[0];
  const float* masks   = (const float*)d_in[1];
  const float* is_train= (const float*)d_in[2];
  const float* conv1_w = (const float*)d_in[3];
  const float* conv1_b = (const float*)d_in[4];
  const float* conv2_w = (const float*)d_in[5];
  const float* conv2_b = (const float*)d_in[6];
  const float* ln1_g   = (const float*)d_in[7];
  const float* ln1_b   = (const float*)d_in[8];
  const float* ln2_g   = (const float*)d_in[9];
  const float* ln2_b   = (const float*)d_in[10];
  const float* Wv_s    = (const float*)d_in[11];
  const float* Wk_s    = (const float*)d_in[12];
  const float* Wq_s    = (const float*)d_in[13];
  const float* Wv_t    = (const float*)d_in[14];
  const float* Wk_t    = (const float*)d_in[15];
  const float* Wq_t    = (const float*)d_in[16];
  const float* Wr      = (const float*)d_in[17];
  const float* br      = (const float*)d_in[18];
  const float* W1      = (const float*)d_in[19];
  const float* b1      = (const float*)d_in[20];
  const float* W2      = (const float*)d_in[21];
  const float* b2      = (const float*)d_in[22];
  float* outp = (float*)d_out;

  // ---- adaptive workspace plan ----
  // x (full residual, 16 b's) + 3 rotating chunk slots + attn + q + k, chunked over CB b's.
  const size_t actb = 2097152;              // per-b activation floats (T*N*C)
  const size_t XFULL = 16 * actb;           // 33,554,432 floats
  int CB = 16;
  while (CB > 1) {
    size_t need = (XFULL + 3 * (size_t)CB * actb + (size_t)CB * 524288
                   + 2 * (size_t)CB * 65536 + 64) * sizeof(float);
    if (need <= ws_size) break;
    CB >>= 1;
  }
  float* wsf  = (float*)d_ws;
  float* x    = wsf;                                  // [16,T,N,C] residual (slot doubles as xsw per chunk)
  float* P1   = x  + XFULL;                           // ln1 out / sp / ln2 out
  float* P2   = P1 + (size_t)CB * actb;               // v_t / x1_partial / x1
  float* P3   = P2 + (size_t)CB * actb;               // tp / v_s / h
  float* attn = P3 + (size_t)CB * actb;               // CB*8*256*256 max
  float* qb   = attn + (size_t)CB * 524288;
  float* kb   = qb + (size_t)CB * 65536;
  float* lossb= kb + (size_t)CB * 65536;

  const int rowsC = CB * 32768;                       // rows per chunk
  const int NC = 16 / CB;

  k_lift<<<131072, 256, 0, stream>>>(values, conv1_w, conv1_b, x);

  for (int i = 0; i < 4; i++) {
    const float* WqS = Wq_s + (size_t)i * 16384 * 256;
    const float* WkS = Wk_s + (size_t)i * 16384 * 256;
    const float* WqT = Wq_t + (size_t)i * 8192 * 256;
    const float* WkT = Wk_t + (size_t)i * 8192 * 256;
    for (int c = 0; c < NC; c++) {
      float* xc = x + (size_t)c * CB * actb;
      // S1: ln1
      k_ln<<<rowsC / 4, 256, 0, stream>>>(xc, P1, ln1_g + i * 64, ln1_b + i * 64);
      // S2: temporal attention (A=T=256, E=N=128) from P1
      k_gemm<<<dim3(rowsC / 64, 1), 256, 0, stream>>>(P1, Wv_t + i * 4096, P2,
                                                      rowsC, 64, 64, nullptr, nullptr, 0);
      k_gemm<<<dim3(CB * 4, 4), 256, 0, stream>>>(P1, WqT, qb, CB * 256, 256, 8192,
                                                  nullptr, nullptr, 0);
      k_gemm<<<dim3(CB * 4, 4), 256, 0, stream>>>(P1, WkT, kb, CB * 256, 256, 8192,
                                                  nullptr, nullptr, 0);
      k_energy<256><<<dim3(256, CB * 8), 256, 0, stream>>>(qb, kb, attn);
      k_softmax<256><<<CB * 512, 256, 0, stream>>>(attn);
      k_attnout<256, 128, false><<<dim3(16, 16, CB * 8), 256, 0, stream>>>(attn, P2, P3);
      // S3: x1_partial = tp @ Wr[64:128] + br + x   -> P2
      k_gemm<<<dim3(rowsC / 64, 1), 256, 0, stream>>>(P3, Wr + i * 8192 + 4096, P2,
                                                      rowsC, 64, 64, br + i * 64, xc, 0);
      // S4: spatial attention (A=N=128, E=T=256); xsw overlays dead x chunk
      k_tr<<<CB * 8192, 256, 0, stream>>>(P1, xc);
      k_gemm<<<dim3(rowsC / 64, 1), 256, 0, stream>>>(xc, Wv_s + i * 4096, P3,
                                                      rowsC, 64, 64, nullptr, nullptr, 0);
      k_gemm<<<dim3(CB * 2, 4), 256, 0, stream>>>(xc, WqS, qb, CB * 128, 256, 16384,
                                                  nullptr, nullptr, 0);
      k_gemm<<<dim3(CB * 2, 4), 256, 0, stream>>>(xc, WkS, kb, CB * 128, 256, 16384,
                                                  nullptr, nullptr, 0);
      k_energy<128><<<dim3(64, CB * 8), 256, 0, stream>>>(qb, kb, attn);
      k_softmax<128><<<CB * 256, 256, 0, stream>>>(attn);
      k_attnout<128, 256, true><<<dim3(32, 8, CB * 8), 256, 0, stream>>>(attn, P3, P1);
      // S5: x1 = sp @ Wr[0:64] + x1_partial   (in-place accumulate into P2)
      k_gemm<<<dim3(rowsC / 64, 1), 256, 0, stream>>>(P1, Wr + i * 8192, P2,
                                                      rowsC, 64, 64, nullptr, P2, 0);
      // S6: ln2 -> P1
      k_ln<<<rowsC / 4, 256, 0, stream>>>(P2, P1, ln2_g + i * 64, ln2_b + i * 64);
      // S7: FFN in 4 row-subchunks; x_new -> xc
      for (int r = 0; r < 4; r++) {
        size_t off = (size_t)r * (rowsC / 4) * 64;
        k_gemm<<<dim3(rowsC / 256, 4), 256, 0, stream>>>(P1 + off, W1 + i * 16384, P3,
                                                         rowsC / 4, 256, 64,
                                                         b1 + i * 256, nullptr, 1);
        k_gemm<<<dim3(rowsC / 256, 1), 256, 0, stream>>>(P3, W2 + i * 16384, xc + off,
                                                         rowsC / 4, 64, 256,
                                                         b2 + i * 64, P2 + off, 0);
      }
    }
  }

  k_zero<<<1, 64, 0, stream>>>(lossb);
  k_out_loss<<<8192, 256, 0, stream>>>(x, conv2_w, conv2_b, values, masks, outp, lossb);
  k_loss_final<<<1, 64, 0, stream>>>(lossb, is_train, outp);
}

// Round 3
// 16828.133 us; speedup vs baseline: 3.6502x; 3.6502x over previous
//
#include <hip/hip_runtime.h>

typedef unsigned short u16;
typedef unsigned int u32;
typedef __attribute__((ext_vector_type(8))) short short8;
typedef __attribute__((ext_vector_type(4))) float f32x4;

#define NEGSC (-1.7677669529663689e8f)   // NEG / sqrt(32)
#define INVS  (0.17677669529663687f)     // 1 / sqrt(32)

__device__ __forceinline__ u16 f2bf(float f) {
  union { float f; u32 u; } x{f};
  u32 r = x.u + 0x7fffu + ((x.u >> 16) & 1u);
  return (u16)(r >> 16);
}

// ---------------- conv1 lift ----------------
__global__ __launch_bounds__(256) void k_lift(const float* __restrict__ values,
    const float* __restrict__ w, const float* __restrict__ b, float* __restrict__ x) {
  int i = blockIdx.x * 256 + threadIdx.x;
  int c = i & 63;
  int r = i >> 6;
  x[i] = values[r] * w[c] + b[c];
}

// ---------------- layernorm over C=64 -> bf16 out ----------------
__global__ __launch_bounds__(256) void k_lnb(const float* __restrict__ in, u16* __restrict__ out,
    const float* __restrict__ g, const float* __restrict__ b) {
  int row = blockIdx.x * 4 + (threadIdx.x >> 6);
  int c = threadIdx.x & 63;
  float v = in[(size_t)row * 64 + c];
  float s = v;
  #pragma unroll
  for (int o = 32; o > 0; o >>= 1) s += __shfl_xor(s, o, 64);
  float mu = s * (1.f / 64.f);
  float d = v - mu;
  float q = d * d;
  #pragma unroll
  for (int o = 32; o > 0; o >>= 1) q += __shfl_xor(q, o, 64);
  out[(size_t)row * 64 + c] = f2bf(d * rsqrtf(q * (1.f / 64.f) + 1e-5f) * g[c] + b[c]);
}

// ------------- bf16 transpose: [CB,T,N,C] -> [CB,N,T,C], int4 (8 bf16) units -------
__global__ __launch_bounds__(256) void k_trb(const int4* __restrict__ in, int4* __restrict__ out) {
  int idx = blockIdx.x * 256 + threadIdx.x;   // over CB*N*T*8
  int c8 = idx & 7;
  int r = idx >> 3;            // (b*N+n)*T + t
  int t = r & 255;
  int bn = r >> 8;
  int n = bn & 127;
  int b = bn >> 7;
  out[idx] = in[(((((b << 8) + t) << 7) + n) << 3) + c8];
}

// ------------- weight cast+transpose: f32 [K,N] -> bf16 [N,K], 32x32 tiles -------
__global__ __launch_bounds__(256) void k_wcast(const float* __restrict__ in, u16* __restrict__ out,
    int K, int N) {
  __shared__ float tile[32][33];
  int k0 = blockIdx.x * 32, n0 = blockIdx.y * 32;
  int tid = threadIdx.x;
  int kr = tid >> 3, nc = (tid & 7) * 4;
  float4 v = *(const float4*)(in + (size_t)(k0 + kr) * N + n0 + nc);
  tile[kr][nc + 0] = v.x; tile[kr][nc + 1] = v.y;
  tile[kr][nc + 2] = v.z; tile[kr][nc + 3] = v.w;
  __syncthreads();
  int nr = tid >> 3, kc = (tid & 7) * 4;
  ushort4 o;
  o.x = f2bf(tile[kc + 0][nr]); o.y = f2bf(tile[kc + 1][nr]);
  o.z = f2bf(tile[kc + 2][nr]); o.w = f2bf(tile[kc + 3][nr]);
  *(ushort4*)(out + (size_t)(n0 + nr) * K + k0 + kc) = o;
}

// ---------------- zero buffer (float4 units) ----------------
__global__ __launch_bounds__(256) void k_zerobuf(float4* __restrict__ p) {
  p[blockIdx.x * 256 + threadIdx.x] = float4{0.f, 0.f, 0.f, 0.f};
}

// =======================================================================
// MFMA GEMM: C[M,N] = A[M,K](bf16,row-major,lda=K) x Bt[N,K](bf16,pre-transposed,ldb)
// BM=128, BN=64, BK=64. 256 threads = 4 waves (2x2). 16x16x32 bf16 MFMA.
// MODE 0: f32 out (+bias,+res); SPLITK -> atomicAdd partials (no bias/res)
// MODE 1: bf16 out = relu(acc + bias)
// MODE 2: vh scatter: row->(b,a,e), col->(h,vu): vh[((b8+h)*E*8 + e*8+vu)*A + a]
// MODE 3: attnout temporal scatter -> out[((b*256+row)*128 + col>>3)*64 + h*8+(col&7)]
// MODE 4: attnout spatial  scatter -> out[((b*256+(col>>3))*128 + row)*64 + h*8+(col&7)]
// batched via blockIdx.z (sA, sB elem strides) when !SPLITK; z = K-segment if SPLITK
// =======================================================================
template<int MODE, bool SPLITK>
__global__ __launch_bounds__(256) void k_mm(
    const u16* __restrict__ A, const u16* __restrict__ Bt, void* Cv,
    const float* __restrict__ bias, const float* res,
    int M, int N, int K, int ldb, int Ksub,
    long long sA, long long sB, int pAsh, int pEsh) {
  __shared__ int4 As4[128 * 8];
  __shared__ int4 Bs4[64 * 8];
  int tid = threadIdx.x;
  int m0 = blockIdx.x * 128, n0 = blockIdx.y * 64;
  int z = blockIdx.z;
  const u16* Ap = A;
  const u16* Bp = Bt;
  int k_beg = 0, k_end = K;
  if (SPLITK) { k_beg = z * Ksub; k_end = k_beg + Ksub; }
  else { Ap += (size_t)z * sA; Bp += (size_t)z * sB; }
  int arow = tid >> 1, aseg = tid & 1;
  int brow = tid >> 2, bq = tid & 3;
  const u16* agp = Ap + (size_t)(m0 + arow) * K + aseg * 32;
  const u16* bgp = Bp + (size_t)(n0 + brow) * ldb + bq * 16;
  int wid = tid >> 6, lane = tid & 63;
  int wr = wid >> 1, wc = wid & 1;
  int l15 = lane & 15, l4 = lane >> 4;
  f32x4 acc[4][2];
  #pragma unroll
  for (int i = 0; i < 4; i++)
    #pragma unroll
    for (int j = 0; j < 2; j++) acc[i][j] = (f32x4){0.f, 0.f, 0.f, 0.f};
  for (int k0 = k_beg; k0 < k_end; k0 += 64) {
    int4 a0 = *(const int4*)(agp + k0);
    int4 a1 = *(const int4*)(agp + k0 + 8);
    int4 a2 = *(const int4*)(agp + k0 + 16);
    int4 a3 = *(const int4*)(agp + k0 + 24);
    int4 b0 = *(const int4*)(bgp + k0);
    int4 b1 = *(const int4*)(bgp + k0 + 8);
    __syncthreads();                       // previous iter's reads done
    int s0 = aseg * 4, sw = arow & 7;
    As4[arow * 8 + ((s0 + 0) ^ sw)] = a0;
    As4[arow * 8 + ((s0 + 1) ^ sw)] = a1;
    As4[arow * 8 + ((s0 + 2) ^ sw)] = a2;
    As4[arow * 8 + ((s0 + 3) ^ sw)] = a3;
    int swb = brow & 7;
    Bs4[brow * 8 + ((bq * 2 + 0) ^ swb)] = b0;
    Bs4[brow * 8 + ((bq * 2 + 1) ^ swb)] = b1;
    __syncthreads();
    #pragma unroll
    for (int kk = 0; kk < 2; kk++) {
      short8 af[4], bf[2];
      #pragma unroll
      for (int mi = 0; mi < 4; mi++) {
        int row = wr * 64 + mi * 16 + l15;
        af[mi] = *(const short8*)&As4[row * 8 + ((kk * 4 + l4) ^ (row & 7))];
      }
      #pragma unroll
      for (int ni = 0; ni < 2; ni++) {
        int row = wc * 32 + ni * 16 + l15;
        bf[ni] = *(const short8*)&Bs4[row * 8 + ((kk * 4 + l4) ^ (row & 7))];
      }
      #pragma unroll
      for (int mi = 0; mi < 4; mi++)
        #pragma unroll
        for (int ni = 0; ni < 2; ni++)
          acc[mi][ni] = __builtin_amdgcn_mfma_f32_16x16x32_bf16(af[mi], bf[ni], acc[mi][ni], 0, 0, 0);
    }
  }
  // ---- epilogue ----
  int b_z = z >> 3, h_z = z & 7;
  #pragma unroll
  for (int mi = 0; mi < 4; mi++) {
    #pragma unroll
    for (int ni = 0; ni < 2; ni++) {
      #pragma unroll
      for (int j = 0; j < 4; j++) {
        int row = m0 + wr * 64 + mi * 16 + l4 * 4 + j;
        int col = n0 + wc * 32 + ni * 16 + l15;
        float v = acc[mi][ni][j];
        if constexpr (MODE == 0) {
          float* C = (float*)Cv;
          if (SPLITK) {
            atomicAdd(&C[(size_t)row * N + col], v);
          } else {
            if (bias) v += bias[col];
            if (res)  v += res[(size_t)row * N + col];
            C[(size_t)row * N + col] = v;
          }
        } else if constexpr (MODE == 1) {
          u16* C = (u16*)Cv;
          v += bias[col];
          v = fmaxf(v, 0.f);
          C[(size_t)row * N + col] = f2bf(v);
        } else if constexpr (MODE == 2) {
          u16* C = (u16*)Cv;
          int bb = row >> 15;                       // A*E = 32768 always
          int a  = (row >> pEsh) & ((1 << pAsh) - 1);
          int e  = row & ((1 << pEsh) - 1);
          int h  = col >> 3, vu = col & 7;
          size_t idx = ((((size_t)(bb * 8 + h) << (pEsh + 3)) + (e << 3) + vu) << pAsh) + a;
          C[idx] = f2bf(v);
        } else if constexpr (MODE == 3) {
          u16* C = (u16*)Cv;
          C[(((size_t)(b_z * 256 + row) * 128) + (col >> 3)) * 64 + h_z * 8 + (col & 7)] = f2bf(v);
        } else if constexpr (MODE == 4) {
          u16* C = (u16*)Cv;
          C[(((size_t)(b_z * 256 + (col >> 3)) * 128) + row) * 64 + h_z * 8 + (col & 7)] = f2bf(v);
        }
      }
    }
  }
}

// ---------------- energy: e[bh,q,k] = (q.k)*INVS, diag = NEG*INVS (f32 q/k) ---------
template<int A>
__global__ __launch_bounds__(256) void k_energy(const float* __restrict__ q,
    const float* __restrict__ k, float* __restrict__ e) {
  constexpr int SH = (A == 128) ? 7 : 8;
  int bh = blockIdx.y;
  int b = bh >> 3, h = bh & 7;
  int idx = blockIdx.x * 256 + threadIdx.x;
  int kk = idx & (A - 1);
  int qq = idx >> SH;
  const float4* qr = (const float4*)(q + (size_t)(b * A + qq) * 256 + h * 32);
  const float4* kr = (const float4*)(k + (size_t)(b * A + kk) * 256 + h * 32);
  float s = 0.f;
  #pragma unroll
  for (int d = 0; d < 8; d++) {
    float4 a = qr[d], bb = kr[d];
    s += a.x * bb.x + a.y * bb.y + a.z * bb.z + a.w * bb.w;
  }
  e[((size_t)bh * A + qq) * A + kk] = (qq == kk) ? NEGSC : s * INVS;
}

// ---------------- softmax (f32 in) -> bf16 probs out ----------------
template<int A>
__global__ __launch_bounds__(256) void k_softmax_pb(const float* __restrict__ e,
    u16* __restrict__ pb) {
  int row = blockIdx.x * 4 + (threadIdx.x >> 6);
  int lane = threadIdx.x & 63;
  const float* p = e + (size_t)row * A;
  constexpr int NVv = A / 64;
  float vals[NVv];
  float mx = -3e38f;
  #pragma unroll
  for (int j = 0; j < NVv; j++) { vals[j] = p[lane + j * 64]; mx = fmaxf(mx, vals[j]); }
  #pragma unroll
  for (int o = 32; o > 0; o >>= 1) mx = fmaxf(mx, __shfl_xor(mx, o, 64));
  float s = 0.f;
  #pragma unroll
  for (int j = 0; j < NVv; j++) { vals[j] = __expf(vals[j] - mx); s += vals[j]; }
  #pragma unroll
  for (int o = 32; o > 0; o >>= 1) s += __shfl_xor(s, o, 64);
  float r = 1.f / s;
  #pragma unroll
  for (int j = 0; j < NVv; j++) pb[(size_t)row * A + lane + j * 64] = f2bf(vals[j] * r);
}

// ---------------- zero loss accumulators ----------------
__global__ void k_zero(float* __restrict__ p) {
  if (threadIdx.x < 32) p[threadIdx.x] = 0.f;
}

// ---------------- conv2 + masked MSE partial sums ----------------
__global__ __launch_bounds__(256) void k_out_loss(const float* __restrict__ x,
    const float* __restrict__ w, const float* __restrict__ cb,
    const float* __restrict__ values, const float* __restrict__ masks,
    float* __restrict__ outp, float* __restrict__ acc) {
  int wid = threadIdx.x >> 6, lane = threadIdx.x & 63;
  float lnum = 0.f, lden = 0.f;
  int base = blockIdx.x * 64;
  for (int g = 0; g < 16; g++) {
    int row = base + g * 4 + wid;
    float v = x[(size_t)row * 64 + lane] * w[lane];
    #pragma unroll
    for (int o = 32; o > 0; o >>= 1) v += __shfl_xor(v, o, 64);
    if (lane == 0) {
      float o = v + cb[0];
      outp[row] = o;
      float m = masks[row];
      float dd = o - values[row];
      lnum += m * dd * dd;
      lden += m;
    }
  }
  __shared__ float sn[4], sd[4];
  if (lane == 0) { sn[wid] = lnum; sd[wid] = lden; }
  __syncthreads();
  if (threadIdx.x == 0) {
    int b = base >> 15;
    atomicAdd(&acc[2 * b],     sn[0] + sn[1] + sn[2] + sn[3]);
    atomicAdd(&acc[2 * b + 1], sd[0] + sd[1] + sd[2] + sd[3]);
  }
}

__global__ void k_loss_final(const float* __restrict__ acc,
    const float* __restrict__ is_train, float* __restrict__ outp) {
  if (threadIdx.x == 0) {
    float s = 0.f, st = 0.f;
    for (int b = 0; b < 16; b++) {
      s  += (acc[2 * b] / acc[2 * b + 1]) * is_train[b];
      st += is_train[b];
    }
    outp[(size_t)16 * 256 * 128] = s / (st + 1e-5f);
  }
}

extern "C" void kernel_launch(void* const* d_in, const int* in_sizes, int n_in,
                              void* d_out, int out_size, void* d_ws, size_t ws_size,
                              hipStream_t stream) {
  const float* values  = (const float*)d_in[0];
  const float* masks   = (const float*)d_in[1];
  const float* is_train= (const float*)d_in[2];
  const float* conv1_w = (const float*)d_in[3];
  const float* conv1_b = (const float*)d_in[4];
  const float* conv2_w = (const float*)d_in[5];
  const float* conv2_b = (const float*)d_in[6];
  const float* ln1_g   = (const float*)d_in[7];
  const float* ln1_b   = (const float*)d_in[8];
  const float* ln2_g   = (const float*)d_in[9];
  const float* ln2_b   = (const float*)d_in[10];
  const float* Wv_s    = (const float*)d_in[11];
  const float* Wk_s    = (const float*)d_in[12];
  const float* Wq_s    = (const float*)d_in[13];
  const float* Wv_t    = (const float*)d_in[14];
  const float* Wk_t    = (const float*)d_in[15];
  const float* Wq_t    = (const float*)d_in[16];
  const float* Wr      = (const float*)d_in[17];
  const float* br      = (const float*)d_in[18];
  const float* W1      = (const float*)d_in[19];
  const float* b1      = (const float*)d_in[20];
  const float* W2      = (const float*)d_in[21];
  const float* b2      = (const float*)d_in[22];
  float* outp = (float*)d_out;

  // ---------- arena ----------
  const size_t perb = 2097152;   // T*N*C elems per batch-elem
  char* base = (char*)d_ws;
  size_t off = 0;
  auto alloc = [&](size_t bytes) { char* p = base + off; off += (bytes + 255) & ~(size_t)255; return p; };
  float* x      = (float*)alloc(16 * perb * 4);          // residual stream (full batch)
  u16* wq_s_b   = (u16*)alloc(4 * 4194304 * 2);
  u16* wk_s_b   = (u16*)alloc(4 * 4194304 * 2);
  u16* wq_t_b   = (u16*)alloc(4 * 2097152 * 2);
  u16* wk_t_b   = (u16*)alloc(4 * 2097152 * 2);
  u16* wv_s_b   = (u16*)alloc(4 * 4096 * 2);
  u16* wv_t_b   = (u16*)alloc(4 * 4096 * 2);
  u16* wr_b     = (u16*)alloc(4 * 8192 * 2);
  u16* w1_b     = (u16*)alloc(4 * 16384 * 2);
  u16* w2_b     = (u16*)alloc(4 * 16384 * 2);
  float* lossb  = (float*)alloc(32 * 4);
  size_t fixed = off;
  // per-b bytes: 5 bf16 act bufs + x1 f32 + q/k f32 + attnE f32 + Pb bf16
  size_t perb_bytes = perb * 2 * 5 + perb * 4 + 65536 * 4 * 2 + 524288 * 4 + 524288 * 2;
  int CB = 16;
  while (CB > 1 && fixed + (size_t)CB * perb_bytes > ws_size) CB >>= 1;
  u16* xnb   = (u16*)alloc((size_t)CB * perb * 2);   // also tpb
  u16* xswb  = (u16*)alloc((size_t)CB * perb * 2);   // also spb
  u16* x2b   = (u16*)alloc((size_t)CB * perb * 2);
  u16* hb    = (u16*)alloc((size_t)CB * perb * 2);
  u16* vhT   = (u16*)alloc((size_t)CB * perb * 2);
  float* x1  = (float*)alloc((size_t)CB * perb * 4);
  float* qb  = (float*)alloc((size_t)CB * 65536 * 4);
  float* kb  = (float*)alloc((size_t)CB * 65536 * 4);
  float* attnE = (float*)alloc((size_t)CB * 524288 * 4);
  u16* Pb    = (u16*)alloc((size_t)CB * 524288 * 2);
  u16* tpb = xnb;
  u16* spb = xswb;

  const int rowsC = CB * 32768;
  const int NC = 16 / CB;

  // ---------- weight prep: cast + transpose ----------
  struct WDesc { const float* src; u16* dst; int K, N; size_t stride_in, stride_out; };
  WDesc wd[9] = {
    { Wq_s, wq_s_b, 16384, 256, 16384u * 256, 4194304 },
    { Wk_s, wk_s_b, 16384, 256, 16384u * 256, 4194304 },
    { Wq_t, wq_t_b,  8192, 256,  8192u * 256, 2097152 },
    { Wk_t, wk_t_b,  8192, 256,  8192u * 256, 2097152 },
    { Wv_s, wv_s_b,    64,  64,  4096,        4096 },
    { Wv_t, wv_t_b,    64,  64,  4096,        4096 },
    { Wr,   wr_b,     128,  64,  8192,        8192 },
    { W1,   w1_b,      64, 256, 16384,       16384 },
    { W2,   w2_b,     256,  64, 16384,       16384 },
  };
  for (int w = 0; w < 9; w++)
    for (int l = 0; l < 4; l++)
      k_wcast<<<dim3(wd[w].K / 32, wd[w].N / 32), 256, 0, stream>>>(
          wd[w].src + (size_t)l * wd[w].stride_in, wd[w].dst + (size_t)l * wd[w].stride_out,
          wd[w].K, wd[w].N);

  k_lift<<<131072, 256, 0, stream>>>(values, conv1_w, conv1_b, x);

  for (int i = 0; i < 4; i++) {
    for (int c = 0; c < NC; c++) {
      float* xc = x + (size_t)c * CB * perb;
      // ln1 -> xnb (bf16), transpose -> xswb
      k_lnb<<<rowsC / 4, 256, 0, stream>>>(xc, xnb, ln1_g + i * 64, ln1_b + i * 64);
      k_trb<<<CB * 1024, 256, 0, stream>>>((const int4*)xnb, (int4*)xswb);
      // ---- temporal attention (A=T=256, E=N=128) ----
      k_zerobuf<<<CB * 128, 256, 0, stream>>>((float4*)qb);   // zeros qb+kb (contiguous)
      k_mm<0, true><<<dim3(CB * 2, 4, 8), 256, 0, stream>>>(
          xnb, wq_t_b + (size_t)i * 2097152, qb, nullptr, nullptr,
          CB * 256, 256, 8192, 8192, 1024, 0, 0, 0, 0);
      k_mm<0, true><<<dim3(CB * 2, 4, 8), 256, 0, stream>>>(
          xnb, wk_t_b + (size_t)i * 2097152, kb, nullptr, nullptr,
          CB * 256, 256, 8192, 8192, 1024, 0, 0, 0, 0);
      k_mm<2, false><<<dim3(rowsC / 128, 1, 1), 256, 0, stream>>>(
          xnb, wv_t_b + (size_t)i * 4096, vhT, nullptr, nullptr,
          rowsC, 64, 64, 64, 0, 0, 0, 8, 7);
      k_energy<256><<<dim3(256, CB * 8), 256, 0, stream>>>(qb, kb, attnE);
      k_softmax_pb<256><<<CB * 512, 256, 0, stream>>>(attnE, Pb);
      k_mm<3, false><<<dim3(2, 16, CB * 8), 256, 0, stream>>>(
          Pb, vhT, tpb, nullptr, nullptr,
          256, 1024, 256, 256, 0, 65536, 262144, 0, 0);
      // ---- spatial attention (A=N=128, E=T=256) ----
      k_zerobuf<<<CB * 128, 256, 0, stream>>>((float4*)qb);
      k_mm<0, true><<<dim3(CB, 4, 16), 256, 0, stream>>>(
          xswb, wq_s_b + (size_t)i * 4194304, qb, nullptr, nullptr,
          CB * 128, 256, 16384, 16384, 1024, 0, 0, 0, 0);
      k_mm<0, true><<<dim3(CB, 4, 16), 256, 0, stream>>>(
          xswb, wk_s_b + (size_t)i * 4194304, kb, nullptr, nullptr,
          CB * 128, 256, 16384, 16384, 1024, 0, 0, 0, 0);
      k_mm<2, false><<<dim3(rowsC / 128, 1, 1), 256, 0, stream>>>(
          xswb, wv_s_b + (size_t)i * 4096, vhT, nullptr, nullptr,
          rowsC, 64, 64, 64, 0, 0, 0, 7, 8);
      k_energy<128><<<dim3(64, CB * 8), 256, 0, stream>>>(qb, kb, attnE);
      k_softmax_pb<128><<<CB * 256, 256, 0, stream>>>(attnE, Pb);
      k_mm<4, false><<<dim3(1, 32, CB * 8), 256, 0, stream>>>(
          Pb, vhT, spb, nullptr, nullptr,
          128, 2048, 128, 128, 0, 16384, 262144, 0, 0);
      // ---- merge: x1 = sp @ Wr_top + tp @ Wr_bot + br + x ----
      k_mm<0, false><<<dim3(rowsC / 128, 1, 1), 256, 0, stream>>>(
          spb, wr_b + (size_t)i * 8192, x1, br + i * 64, xc,
          rowsC, 64, 64, 128, 0, 0, 0, 0, 0);
      k_mm<0, false><<<dim3(rowsC / 128, 1, 1), 256, 0, stream>>>(
          tpb, wr_b + (size_t)i * 8192 + 64, x1, nullptr, x1,
          rowsC, 64, 64, 128, 0, 0, 0, 0, 0);
      // ---- ln2 -> x2b ----
      k_lnb<<<rowsC / 4, 256, 0, stream>>>(x1, x2b, ln2_g + i * 64, ln2_b + i * 64);
      // ---- FFN in 4 row-subchunks ----
      for (int r = 0; r < 4; r++) {
        size_t roff = (size_t)r * (rowsC / 4);
        k_mm<1, false><<<dim3(rowsC / 512, 4, 1), 256, 0, stream>>>(
            x2b + roff * 64, w1_b + (size_t)i * 16384, hb, b1 + i * 256, nullptr,
            rowsC / 4, 256, 64, 64, 0, 0, 0, 0, 0);
        k_mm<0, false><<<dim3(rowsC / 512, 1, 1), 256, 0, stream>>>(
            hb, w2_b + (size_t)i * 16384, xc + roff * 64, b2 + i * 64, x1 + roff * 64,
            rowsC / 4, 64, 256, 256, 0, 0, 0, 0, 0);
      }
    }
  }

  k_zero<<<1, 64, 0, stream>>>(lossb);
  k_out_loss<<<8192, 256, 0, stream>>>(x, conv2_w, conv2_b, values, masks, outp, lossb);
  k_loss_final<<<1, 64, 0, stream>>>(lossb, is_train, outp);
}

// Round 4
// 15153.775 us; speedup vs baseline: 4.0535x; 1.1105x over previous
//
#include <hip/hip_runtime.h>

typedef unsigned short u16;
typedef unsigned int u32;
typedef __attribute__((ext_vector_type(8))) short short8;
typedef __attribute__((ext_vector_type(4))) float f32x4;

#define NEGSC (-1.7677669529663689e8f)   // NEG / sqrt(32)
#define INVS  (0.17677669529663687f)     // 1 / sqrt(32)

__device__ __forceinline__ u16 f2bf(float f) {
  union { float f; u32 u; } x{f};
  u32 r = x.u + 0x7fffu + ((x.u >> 16) & 1u);
  return (u16)(r >> 16);
}

// async global->LDS 16B: per-lane global src, wave-uniform LDS base (+lane*16 by HW)
__device__ __forceinline__ void gll16(const void* g, void* l) {
#if defined(__has_builtin) && __has_builtin(__builtin_amdgcn_global_load_lds)
  __builtin_amdgcn_global_load_lds(
      (const __attribute__((address_space(1))) void*)g,
      (__attribute__((address_space(3))) void*)l, 16, 0, 0);
#else
  int lane = threadIdx.x & 63;
  *(int4*)((char*)l + lane * 16) = *(const int4*)((const char*)g);
#endif
}

// ---------------- conv1 lift ----------------
__global__ __launch_bounds__(256) void k_lift(const float* __restrict__ values,
    const float* __restrict__ w, const float* __restrict__ b, float* __restrict__ x) {
  int i = blockIdx.x * 256 + threadIdx.x;
  int c = i & 63;
  int r = i >> 6;
  x[i] = values[r] * w[c] + b[c];
}

// ------- layernorm over C=64 -> bf16 out (+ optional transposed copy) -------
__global__ __launch_bounds__(256) void k_lnb(const float* __restrict__ in, u16* __restrict__ out,
    u16* __restrict__ out2, const float* __restrict__ g, const float* __restrict__ b) {
  int row = blockIdx.x * 4 + (threadIdx.x >> 6);
  int c = threadIdx.x & 63;
  float v = in[(size_t)row * 64 + c];
  float s = v;
  #pragma unroll
  for (int o = 32; o > 0; o >>= 1) s += __shfl_xor(s, o, 64);
  float mu = s * (1.f / 64.f);
  float d = v - mu;
  float q = d * d;
  #pragma unroll
  for (int o = 32; o > 0; o >>= 1) q += __shfl_xor(q, o, 64);
  u16 val = f2bf(d * rsqrtf(q * (1.f / 64.f) + 1e-5f) * g[c] + b[c]);
  out[(size_t)row * 64 + c] = val;
  if (out2) {
    int rl = row & 32767;
    int bb = row >> 15;
    int t = rl >> 7, n = rl & 127;
    out2[(((size_t)(bb * 128 + n)) * 256 + t) * 64 + c] = val;
  }
}

// ------------- weight cast+transpose: f32 [K,N] -> bf16 [N,K], 32x32 tiles -------
__global__ __launch_bounds__(256) void k_wcast(const float* __restrict__ in, u16* __restrict__ out,
    int K, int N) {
  __shared__ float tile[32][33];
  int k0 = blockIdx.x * 32, n0 = blockIdx.y * 32;
  int tid = threadIdx.x;
  int kr = tid >> 3, nc = (tid & 7) * 4;
  float4 v = *(const float4*)(in + (size_t)(k0 + kr) * N + n0 + nc);
  tile[kr][nc + 0] = v.x; tile[kr][nc + 1] = v.y;
  tile[kr][nc + 2] = v.z; tile[kr][nc + 3] = v.w;
  __syncthreads();
  int nr = tid >> 3, kc = (tid & 7) * 4;
  ushort4 o;
  o.x = f2bf(tile[kc + 0][nr]); o.y = f2bf(tile[kc + 1][nr]);
  o.z = f2bf(tile[kc + 2][nr]); o.w = f2bf(tile[kc + 3][nr]);
  *(ushort4*)(out + (size_t)(n0 + nr) * K + k0 + kc) = o;
}

// =======================================================================
// MFMA GEMM: C[M,N] = A[M,K](bf16 row-major, lda) x Bt[N,K](bf16 pre-T, ldb)
// BM=128, BN=64, BK=64, 256 thr = 4 waves. global_load_lds staging with
// pre-swizzled source (LDS linear, read XOR-swizzled).
// SPLITK: z=(ty<<ksh)+seg -> Bp=Bt+ty*sB, k in [seg*Ksub, ...); out partials
//         at Cv + z*M*N (f32, no bias/res).
// else:   Ap += z*sA, Bp += z*sB (batched).
// A2 (optional): rows for k0 >= Kturn come from A2 (concat-K, same lda).
// MODE 0: f32 out (+bias,+res; res may alias out)
// MODE 1: bf16 out = relu(acc+bias)
// MODE 2: vh scatter  [bh][(e*8+vu)][a]
// MODE 3: temporal attnout -> out[((b*256+row)*128+(col>>3))*64 + h*8+(col&7)]
// MODE 4: spatial  attnout -> out[((b*256+(col>>3))*128+row)*64 + h*8+(col&7)]
// =======================================================================
template<int MODE, bool SPLITK>
__global__ __launch_bounds__(256) void k_mm(
    const u16* __restrict__ A, const u16* __restrict__ A2, const u16* __restrict__ Bt,
    void* Cv, const float* __restrict__ bias, const float* res,
    int M, int N, int K, int lda, int ldb, int Ksub, int ksh, int Kturn,
    long long sA, long long sB, int pAsh, int pEsh) {
  __shared__ __align__(16) u16 As[128 * 64];
  __shared__ __align__(16) u16 Bs[64 * 64];
  int tid = threadIdx.x;
  int wid = tid >> 6, lane = tid & 63;
  int m0 = blockIdx.x * 128, n0 = blockIdx.y * 64;
  int z = blockIdx.z;
  const u16* Ap = A;
  const u16* Bp = Bt;
  int k_beg = 0, k_end = K;
  if (SPLITK) {
    int ty = z >> ksh;
    int seg = z - (ty << ksh);
    Bp += (size_t)ty * sB;
    k_beg = seg * Ksub;
    k_end = k_beg + Ksub;
  } else {
    Ap += (size_t)z * sA;
    Bp += (size_t)z * sB;
  }
  // per-lane staging geometry (source pre-swizzled: slot j holds global seg j^(row&7))
  int lrow = lane >> 3;                // 0..7 within 8-row group
  int lseg = (lane & 7) ^ lrow;        // swizzled 16B segment
  size_t aoff[4];
  #pragma unroll
  for (int i = 0; i < 4; i++) {
    int g = wid * 4 + i;
    aoff[i] = (size_t)(m0 + g * 8 + lrow) * lda + lseg * 8;
  }
  size_t boff[2];
  #pragma unroll
  for (int i = 0; i < 2; i++) {
    int g = wid * 2 + i;
    boff[i] = (size_t)(n0 + g * 8 + lrow) * ldb + lseg * 8;
  }
  int wr = wid >> 1, wc = wid & 1;
  int l15 = lane & 15, l4 = lane >> 4;
  f32x4 acc[4][2];
  #pragma unroll
  for (int i = 0; i < 4; i++)
    #pragma unroll
    for (int j = 0; j < 2; j++) acc[i][j] = (f32x4){0.f, 0.f, 0.f, 0.f};
  for (int k0 = k_beg; k0 < k_end; k0 += 64) {
    const u16* Asrc = Ap;
    int ka = k0;
    if (A2 != nullptr && k0 >= Kturn) { Asrc = A2; ka = k0 - Kturn; }
    __syncthreads();   // all waves done reading LDS from previous step
    #pragma unroll
    for (int i = 0; i < 4; i++)
      gll16(Asrc + aoff[i] + ka, (char*)As + wid * 4096 + i * 1024);
    #pragma unroll
    for (int i = 0; i < 2; i++)
      gll16(Bp + boff[i] + k0, (char*)Bs + wid * 2048 + i * 1024);
    __syncthreads();   // drains vmcnt: staged data visible
    #pragma unroll
    for (int kk = 0; kk < 2; kk++) {
      short8 af[4], bf2[2];
      #pragma unroll
      for (int mi = 0; mi < 4; mi++) {
        int r = wr * 64 + mi * 16 + l15;
        af[mi] = *(const short8*)((const char*)As + r * 128 + (((kk * 4 + l4) ^ (r & 7)) * 16));
      }
      #pragma unroll
      for (int ni = 0; ni < 2; ni++) {
        int r = wc * 32 + ni * 16 + l15;
        bf2[ni] = *(const short8*)((const char*)Bs + r * 128 + (((kk * 4 + l4) ^ (r & 7)) * 16));
      }
      #pragma unroll
      for (int mi = 0; mi < 4; mi++)
        #pragma unroll
        for (int ni = 0; ni < 2; ni++)
          acc[mi][ni] = __builtin_amdgcn_mfma_f32_16x16x32_bf16(af[mi], bf2[ni], acc[mi][ni], 0, 0, 0);
    }
  }
  // ---- epilogue ----
  int b_z = z >> 3, h_z = z & 7;
  #pragma unroll
  for (int mi = 0; mi < 4; mi++) {
    #pragma unroll
    for (int ni = 0; ni < 2; ni++) {
      #pragma unroll
      for (int j = 0; j < 4; j++) {
        int row = m0 + wr * 64 + mi * 16 + l4 * 4 + j;
        int col = n0 + wc * 32 + ni * 16 + l15;
        float v = acc[mi][ni][j];
        if constexpr (MODE == 0) {
          if (SPLITK) {
            float* C = (float*)Cv + (size_t)z * M * N;
            C[(size_t)row * N + col] = v;
          } else {
            float* C = (float*)Cv;
            if (bias) v += bias[col];
            if (res)  v += res[(size_t)row * N + col];
            C[(size_t)row * N + col] = v;
          }
        } else if constexpr (MODE == 1) {
          u16* C = (u16*)Cv;
          v += bias[col];
          v = fmaxf(v, 0.f);
          C[(size_t)row * N + col] = f2bf(v);
        } else if constexpr (MODE == 2) {
          u16* C = (u16*)Cv;
          int bb = row >> 15;
          int a  = (row >> pEsh) & ((1 << pAsh) - 1);
          int e  = row & ((1 << pEsh) - 1);
          int h  = col >> 3, vu = col & 7;
          size_t idx = ((((size_t)(bb * 8 + h) << (pEsh + 3)) + (e << 3) + vu) << pAsh) + a;
          C[idx] = f2bf(v);
        } else if constexpr (MODE == 3) {
          u16* C = (u16*)Cv;
          C[(((size_t)(b_z * 256 + row) * 128) + (col >> 3)) * 64 + h_z * 8 + (col & 7)] = f2bf(v);
        } else if constexpr (MODE == 4) {
          u16* C = (u16*)Cv;
          C[(((size_t)(b_z * 256 + (col >> 3)) * 128) + row) * 64 + h_z * 8 + (col & 7)] = f2bf(v);
        }
      }
    }
  }
}

// ---------------- split-K reduce: parts[2][S][M][256] -> qb,kb ----------------
__global__ __launch_bounds__(256) void k_redqk(const float4* __restrict__ parts,
    float4* __restrict__ qb, float4* __restrict__ kb, int M, int S) {
  int i = blockIdx.x * 256 + threadIdx.x;       // over 2*M*64 float4s
  int half = M * 64;
  int ty = (i >= half) ? 1 : 0;
  int r = i - ty * half;
  const float4* p = parts + (size_t)ty * S * half + r;
  float4 s = p[0];
  for (int sg = 1; sg < S; sg++) {
    float4 v = p[(size_t)sg * half];
    s.x += v.x; s.y += v.y; s.z += v.z; s.w += v.w;
  }
  (ty ? kb : qb)[r] = s;
}

// ------- fused energy+softmax: Pb[bh][q][k] = softmax_k((q.k)*INVS, diag=NEG) -------
template<int A>
__global__ __launch_bounds__(256) void k_esm(const float* __restrict__ qb,
    const float* __restrict__ kb, u16* __restrict__ Pb) {
  __shared__ float Kld[A][36];
  __shared__ float Qld[32][36];
  int bh = blockIdx.y;
  int b = bh >> 3, h = bh & 7;
  int q0 = blockIdx.x * 32;
  int tid = threadIdx.x;
  const float* kbase = kb + ((size_t)b * A) * 256 + h * 32;
  #pragma unroll
  for (int p = 0; p < A / 32; p++) {
    int row = p * 32 + (tid >> 3);
    int c4 = tid & 7;
    float4 v = *(const float4*)(kbase + (size_t)row * 256 + c4 * 4);
    *(float4*)&Kld[row][c4 * 4] = v;
  }
  {
    int row = tid >> 3, c4 = tid & 7;
    float4 v = *(const float4*)(qb + ((size_t)b * A + q0 + row) * 256 + h * 32 + c4 * 4);
    *(float4*)&Qld[row][c4 * 4] = v;
  }
  __syncthreads();
  int w = tid >> 6, lane = tid & 63;
  constexpr int NJ = A / 64;
  for (int rr = 0; rr < 8; rr++) {
    int rl = w * 8 + rr;
    int qrow = q0 + rl;
    float qv[32];
    #pragma unroll
    for (int c4 = 0; c4 < 8; c4++) {
      float4 v = *(const float4*)&Qld[rl][c4 * 4];
      qv[c4 * 4 + 0] = v.x; qv[c4 * 4 + 1] = v.y;
      qv[c4 * 4 + 2] = v.z; qv[c4 * 4 + 3] = v.w;
    }
    float vals[NJ];
    float mx = -3e38f;
    #pragma unroll
    for (int jj = 0; jj < NJ; jj++) {
      int kidx = lane + jj * 64;
      float s = 0.f;
      #pragma unroll
      for (int c4 = 0; c4 < 8; c4++) {
        float4 v = *(const float4*)&Kld[kidx][c4 * 4];
        s += qv[c4 * 4 + 0] * v.x + qv[c4 * 4 + 1] * v.y
           + qv[c4 * 4 + 2] * v.z + qv[c4 * 4 + 3] * v.w;
      }
      vals[jj] = (kidx == qrow) ? NEGSC : s * INVS;
      mx = fmaxf(mx, vals[jj]);
    }
    #pragma unroll
    for (int o = 32; o > 0; o >>= 1) mx = fmaxf(mx, __shfl_xor(mx, o, 64));
    float ssum = 0.f;
    #pragma unroll
    for (int jj = 0; jj < NJ; jj++) { vals[jj] = __expf(vals[jj] - mx); ssum += vals[jj]; }
    #pragma unroll
    for (int o = 32; o > 0; o >>= 1) ssum += __shfl_xor(ssum, o, 64);
    float rs = 1.f / ssum;
    #pragma unroll
    for (int jj = 0; jj < NJ; jj++)
      Pb[((size_t)bh * A + qrow) * A + lane + jj * 64] = f2bf(vals[jj] * rs);
  }
}

// ---------------- zero loss accumulators ----------------
__global__ void k_zero(float* __restrict__ p) {
  if (threadIdx.x < 32) p[threadIdx.x] = 0.f;
}

// ---------------- conv2 + masked MSE partial sums ----------------
__global__ __launch_bounds__(256) void k_out_loss(const float* __restrict__ x,
    const float* __restrict__ w, const float* __restrict__ cb,
    const float* __restrict__ values, const float* __restrict__ masks,
    float* __restrict__ outp, float* __restrict__ acc) {
  int wid = threadIdx.x >> 6, lane = threadIdx.x & 63;
  float lnum = 0.f, lden = 0.f;
  int base = blockIdx.x * 64;
  for (int g = 0; g < 16; g++) {
    int row = base + g * 4 + wid;
    float v = x[(size_t)row * 64 + lane] * w[lane];
    #pragma unroll
    for (int o = 32; o > 0; o >>= 1) v += __shfl_xor(v, o, 64);
    if (lane == 0) {
      float o = v + cb[0];
      outp[row] = o;
      float m = masks[row];
      float dd = o - values[row];
      lnum += m * dd * dd;
      lden += m;
    }
  }
  __shared__ float sn[4], sd[4];
  if (lane == 0) { sn[wid] = lnum; sd[wid] = lden; }
  __syncthreads();
  if (threadIdx.x == 0) {
    int b = base >> 15;
    atomicAdd(&acc[2 * b],     sn[0] + sn[1] + sn[2] + sn[3]);
    atomicAdd(&acc[2 * b + 1], sd[0] + sd[1] + sd[2] + sd[3]);
  }
}

__global__ void k_loss_final(const float* __restrict__ acc,
    const float* __restrict__ is_train, float* __restrict__ outp) {
  if (threadIdx.x == 0) {
    float s = 0.f, st = 0.f;
    for (int b = 0; b < 16; b++) {
      s  += (acc[2 * b] / acc[2 * b + 1]) * is_train[b];
      st += is_train[b];
    }
    outp[(size_t)16 * 256 * 128] = s / (st + 1e-5f);
  }
}

extern "C" void kernel_launch(void* const* d_in, const int* in_sizes, int n_in,
                              void* d_out, int out_size, void* d_ws, size_t ws_size,
                              hipStream_t stream) {
  const float* values  = (const float*)d_in[0];
  const float* masks   = (const float*)d_in[1];
  const float* is_train= (const float*)d_in[2];
  const float* conv1_w = (const float*)d_in[3];
  const float* conv1_b = (const float*)d_in[4];
  const float* conv2_w = (const float*)d_in[5];
  const float* conv2_b = (const float*)d_in[6];
  const float* ln1_g   = (const float*)d_in[7];
  const float* ln1_b   = (const float*)d_in[8];
  const float* ln2_g   = (const float*)d_in[9];
  const float* ln2_b   = (const float*)d_in[10];
  const float* Wv_s    = (const float*)d_in[11];
  const float* Wk_s    = (const float*)d_in[12];
  const float* Wq_s    = (const float*)d_in[13];
  const float* Wv_t    = (const float*)d_in[14];
  const float* Wk_t    = (const float*)d_in[15];
  const float* Wq_t    = (const float*)d_in[16];
  const float* Wr      = (const float*)d_in[17];
  const float* br      = (const float*)d_in[18];
  const float* W1      = (const float*)d_in[19];
  const float* b1      = (const float*)d_in[20];
  const float* W2      = (const float*)d_in[21];
  const float* b2      = (const float*)d_in[22];
  float* outp = (float*)d_out;

  // ---------- arena ----------
  const size_t perb = 2097152;   // T*N*C elems per batch-elem
  char* base = (char*)d_ws;
  size_t off = 0;
  auto alloc = [&](size_t bytes) { char* p = base + off; off += (bytes + 255) & ~(size_t)255; return p; };
  float* x      = (float*)alloc(16 * perb * 4);          // residual (f32, full batch); x1 in-place
  u16* wqk_s_b  = (u16*)alloc((size_t)4 * 2 * 4194304 * 2);  // [L][q|k][16384*256]
  u16* wqk_t_b  = (u16*)alloc((size_t)4 * 2 * 2097152 * 2);  // [L][q|k][8192*256]
  u16* wv_s_b   = (u16*)alloc(4 * 4096 * 2);
  u16* wv_t_b   = (u16*)alloc(4 * 4096 * 2);
  u16* wr_b     = (u16*)alloc(4 * 8192 * 2);
  u16* w1_b     = (u16*)alloc(4 * 16384 * 2);
  u16* w2_b     = (u16*)alloc(4 * 16384 * 2);
  float* lossb  = (float*)alloc(32 * 4);
  size_t fixed = off;
  // per-b: xnb 4MB + xswb 4MB + x2b 4MB + hb 4MB + vhT 4MB + qb .25 + kb .25 + parts 2 + Pb 1
  size_t perb_bytes = perb * 2 * 5 + 65536 * 4 * 2 + 2 * 524288 * 4 + 524288 * 2;
  int CB = 16;
  while (CB > 1 && fixed + (size_t)CB * perb_bytes + 4096 > ws_size) CB >>= 1;
  u16* xnb   = (u16*)alloc((size_t)CB * perb * 2);   // ln1 out; later tp
  u16* xswb  = (u16*)alloc((size_t)CB * perb * 2);   // transposed ln1; later sp
  u16* x2b   = (u16*)alloc((size_t)CB * perb * 2);   // ln2 out
  u16* hb    = (u16*)alloc((size_t)CB * perb * 2);   // FFN hidden (1/4 rows at a time)
  u16* vhT   = (u16*)alloc((size_t)CB * perb * 2);   // per-head transposed V
  float* qb  = (float*)alloc((size_t)CB * 65536 * 4);
  float* kb  = (float*)alloc((size_t)CB * 65536 * 4);
  float* parts = (float*)alloc((size_t)CB * 2 * 262144 * 4);  // [2][S][M][256]
  u16* Pb    = (u16*)alloc((size_t)CB * 524288 * 2);
  u16* tpb = xnb;
  u16* spb = xswb;

  const int rowsC = CB * 32768;
  const int NC = 16 / CB;

  // ---------- weight prep: cast + transpose ----------
  struct WDesc { const float* src; u16* dst; int K, N; size_t si, so; };
  WDesc wd[9] = {
    { Wq_s, wqk_s_b,           16384, 256, 16384u * 256, 2u * 4194304 },
    { Wk_s, wqk_s_b + 4194304, 16384, 256, 16384u * 256, 2u * 4194304 },
    { Wq_t, wqk_t_b,            8192, 256,  8192u * 256, 2u * 2097152 },
    { Wk_t, wqk_t_b + 2097152,  8192, 256,  8192u * 256, 2u * 2097152 },
    { Wv_s, wv_s_b,    64,  64,  4096,  4096 },
    { Wv_t, wv_t_b,    64,  64,  4096,  4096 },
    { Wr,   wr_b,     128,  64,  8192,  8192 },
    { W1,   w1_b,      64, 256, 16384, 16384 },
    { W2,   w2_b,     256,  64, 16384, 16384 },
  };
  for (int w = 0; w < 9; w++)
    for (int l = 0; l < 4; l++)
      k_wcast<<<dim3(wd[w].K / 32, wd[w].N / 32), 256, 0, stream>>>(
          wd[w].src + (size_t)l * wd[w].si, wd[w].dst + (size_t)l * wd[w].so,
          wd[w].K, wd[w].N);

  k_lift<<<131072, 256, 0, stream>>>(values, conv1_w, conv1_b, x);

  for (int i = 0; i < 4; i++) {
    for (int c = 0; c < NC; c++) {
      float* xc = x + (size_t)c * CB * perb;
      // ln1 -> xnb + transposed copy -> xswb
      k_lnb<<<rowsC / 4, 256, 0, stream>>>(xc, xnb, xswb, ln1_g + i * 64, ln1_b + i * 64);
      // ---- temporal attention (A=T=256, E=N=128) ----
      k_mm<0, true><<<dim3(CB * 2, 4, 8), 256, 0, stream>>>(      // q&k fused, S=4
          xnb, nullptr, wqk_t_b + (size_t)i * 2 * 2097152, parts, nullptr, nullptr,
          CB * 256, 256, 8192, 8192, 8192, 2048, 2, 0, 0, 2097152, 0, 0);
      k_redqk<<<CB * 128, 256, 0, stream>>>((const float4*)parts, (float4*)qb, (float4*)kb,
                                            CB * 256, 4);
      k_mm<2, false><<<dim3(rowsC / 128, 1, 1), 256, 0, stream>>>(
          xnb, nullptr, wv_t_b + (size_t)i * 4096, vhT, nullptr, nullptr,
          rowsC, 64, 64, 64, 64, 0, 0, 0, 0, 0, 8, 7);
      k_esm<256><<<dim3(8, CB * 8), 256, 0, stream>>>(qb, kb, Pb);
      k_mm<3, false><<<dim3(2, 16, CB * 8), 256, 0, stream>>>(
          Pb, nullptr, vhT, tpb, nullptr, nullptr,
          256, 1024, 256, 256, 256, 0, 0, 0, 65536, 262144, 0, 0);
      // ---- spatial attention (A=N=128, E=T=256) ----
      k_mm<0, true><<<dim3(CB, 4, 16), 256, 0, stream>>>(         // q&k fused, S=8
          xswb, nullptr, wqk_s_b + (size_t)i * 2 * 4194304, parts, nullptr, nullptr,
          CB * 128, 256, 16384, 16384, 16384, 2048, 3, 0, 0, 4194304, 0, 0);
      k_redqk<<<CB * 64, 256, 0, stream>>>((const float4*)parts, (float4*)qb, (float4*)kb,
                                           CB * 128, 8);
      k_mm<2, false><<<dim3(rowsC / 128, 1, 1), 256, 0, stream>>>(
          xswb, nullptr, wv_s_b + (size_t)i * 4096, vhT, nullptr, nullptr,
          rowsC, 64, 64, 64, 64, 0, 0, 0, 0, 0, 7, 8);
      k_esm<128><<<dim3(4, CB * 8), 256, 0, stream>>>(qb, kb, Pb);
      k_mm<4, false><<<dim3(1, 32, CB * 8), 256, 0, stream>>>(
          Pb, nullptr, vhT, spb, nullptr, nullptr,
          128, 2048, 128, 128, 128, 0, 0, 0, 16384, 262144, 0, 0);
      // ---- merge (dual-A concat-K): x1 = sp@Wr_top + tp@Wr_bot + br + x -> xc in place
      k_mm<0, false><<<dim3(rowsC / 128, 1, 1), 256, 0, stream>>>(
          spb, tpb, wr_b + (size_t)i * 8192, xc, br + i * 64, xc,
          rowsC, 64, 128, 64, 128, 0, 0, 64, 0, 0, 0, 0);
      // ---- ln2 -> x2b ----
      k_lnb<<<rowsC / 4, 256, 0, stream>>>(xc, x2b, nullptr, ln2_g + i * 64, ln2_b + i * 64);
      // ---- FFN in 4 row-subchunks; x_new -> xc (residual x1 read from xc, aliased)
      for (int r = 0; r < 4; r++) {
        size_t roff = (size_t)r * (rowsC / 4);
        k_mm<1, false><<<dim3(rowsC / 512, 4, 1), 256, 0, stream>>>(
            x2b + roff * 64, nullptr, w1_b + (size_t)i * 16384, hb, b1 + i * 256, nullptr,
            rowsC / 4, 256, 64, 64, 64, 0, 0, 0, 0, 0, 0, 0);
        k_mm<0, false><<<dim3(rowsC / 512, 1, 1), 256, 0, stream>>>(
            hb, nullptr, w2_b + (size_t)i * 16384, xc + roff * 64, b2 + i * 64,
            (const float*)(xc + roff * 64),
            rowsC / 4, 64, 256, 256, 256, 0, 0, 0, 0, 0, 0, 0);
      }
    }
  }

  k_zero<<<1, 64, 0, stream>>>(lossb);
  k_out_loss<<<8192, 256, 0, stream>>>(x, conv2_w, conv2_b, values, masks, outp, lossb);
  k_loss_final<<<1, 64, 0, stream>>>(lossb, is_train, outp);
}